// Round 1
// baseline (4531.666 us; speedup 1.0000x reference)
//
#include <hip/hip_runtime.h>

#define NN 100000      // nodes
#define NE 1600000     // edges
#define F0 512         // NFEAT
#define F1 128         // NHID
#define F2 64          // NCLASS

// ---------------------------------------------------------------------------
// Tiled fp32 GEMM: C[M,N] = A[M,K] @ B[K,N], N == BN (single column block).
// 256 threads = 16x16; each thread computes TM x TN outputs.
// ---------------------------------------------------------------------------
template<int BM, int BN, int BK, int TM, int TN>
__global__ __launch_bounds__(256)
void gemm_kernel(const float* __restrict__ A, const float* __restrict__ B,
                 float* __restrict__ C, int M, int K, int N)
{
    __shared__ float As[BK][BM + 4];   // A tile stored transposed (k-major)
    __shared__ float Bs[BK][BN];

    const int tx = threadIdx.x & 15;
    const int ty = threadIdx.x >> 4;
    const int row0 = blockIdx.x * BM;

    float acc[TM][TN];
#pragma unroll
    for (int i = 0; i < TM; i++)
#pragma unroll
        for (int j = 0; j < TN; j++) acc[i][j] = 0.f;

    for (int k0 = 0; k0 < K; k0 += BK) {
        // --- stage A tile (BM x BK), transpose into As[k][row] ---
        constexpr int A4 = BM * BK / 4;
        for (int l = threadIdx.x; l < A4; l += 256) {
            int r  = l / (BK / 4);
            int kq = l % (BK / 4);
            int rg = row0 + r; if (rg >= M) rg = M - 1;   // clamp (unused rows)
            float4 v = *(const float4*)(A + (long long)rg * K + k0 + kq * 4);
            As[kq * 4 + 0][r] = v.x;
            As[kq * 4 + 1][r] = v.y;
            As[kq * 4 + 2][r] = v.z;
            As[kq * 4 + 3][r] = v.w;
        }
        // --- stage B tile (BK x BN), direct ---
        constexpr int B4 = BK * BN / 4;
        for (int l = threadIdx.x; l < B4; l += 256) {
            int kr = l / (BN / 4);
            int cq = l % (BN / 4);
            *(float4*)(&Bs[kr][cq * 4]) =
                *(const float4*)(B + (long long)(k0 + kr) * N + cq * 4);
        }
        __syncthreads();

#pragma unroll
        for (int k = 0; k < BK; k++) {
            float a[TM], b[TN];
#pragma unroll
            for (int i = 0; i < TM; i++) a[i] = As[k][ty * TM + i];
#pragma unroll
            for (int j = 0; j < TN; j++) b[j] = Bs[k][tx * TN + j];
#pragma unroll
            for (int i = 0; i < TM; i++)
#pragma unroll
                for (int j = 0; j < TN; j++)
                    acc[i][j] = fmaf(a[i], b[j], acc[i][j]);
        }
        __syncthreads();
    }

    // --- store ---
#pragma unroll
    for (int i = 0; i < TM; i++) {
        int rg = row0 + ty * TM + i;
        if (rg < M) {
#pragma unroll
            for (int j = 0; j < TN; j += 4) {
                float4 v = make_float4(acc[i][j], acc[i][j+1], acc[i][j+2], acc[i][j+3]);
                *(float4*)(C + (long long)rg * N + tx * TN + j) = v;
            }
        }
    }
}

// ---------------------------------------------------------------------------
// Edge scatter-add: agg[dst[e]] += sup[src[e]] * ew[e]
// 2^LOGC threads per edge, each handling one float4 chunk of the feature row.
// ---------------------------------------------------------------------------
template<int LOGC>
__global__ __launch_bounds__(256)
void scatter_kernel(const float4* __restrict__ sup, const int* __restrict__ src,
                    const int* __restrict__ dst, const float* __restrict__ ew,
                    float* __restrict__ agg, int nE)
{
    const int C4 = 1 << LOGC;          // float4 chunks per feature row
    int t = blockIdx.x * 256 + threadIdx.x;
    int e = t >> LOGC;
    int c = t & (C4 - 1);
    if (e >= nE) return;

    int s = src[e];
    int d = dst[e];
    float w = ew[e];
    float4 v = sup[(long long)s * C4 + c];
    float* o = agg + ((long long)d * C4 + c) * 4;
    atomicAdd(o + 0, v.x * w);
    atomicAdd(o + 1, v.y * w);
    atomicAdd(o + 2, v.z * w);
    atomicAdd(o + 3, v.w * w);
}

// ---------------------------------------------------------------------------
// h = leaky_relu(agg + b, 0.01), float4-vectorized. colmask = F/4 - 1.
// ---------------------------------------------------------------------------
__global__ __launch_bounds__(256)
void bias_leaky_kernel(const float4* __restrict__ agg, const float4* __restrict__ b,
                       float4* __restrict__ out, int n4, int colmask)
{
    int i = blockIdx.x * 256 + threadIdx.x;
    if (i >= n4) return;
    float4 v = agg[i];
    float4 bb = b[i & colmask];
    v.x += bb.x; v.y += bb.y; v.z += bb.z; v.w += bb.w;
    v.x = v.x > 0.f ? v.x : 0.01f * v.x;
    v.y = v.y > 0.f ? v.y : 0.01f * v.y;
    v.z = v.z > 0.f ? v.z : 0.01f * v.z;
    v.w = v.w > 0.f ? v.w : 0.01f * v.w;
    out[i] = v;
}

// ---------------------------------------------------------------------------
// Row softmax over 64 classes: one 64-lane wave per node (4 nodes / block).
// ---------------------------------------------------------------------------
__global__ __launch_bounds__(256)
void softmax_kernel(const float* __restrict__ agg, const float* __restrict__ b,
                    float* __restrict__ out, int n)
{
    int node = blockIdx.x * 4 + (threadIdx.x >> 6);
    int lane = threadIdx.x & 63;
    if (node >= n) return;

    float v = agg[(long long)node * 64 + lane] + b[lane];
    float m = v;
#pragma unroll
    for (int off = 32; off; off >>= 1) m = fmaxf(m, __shfl_xor(m, off, 64));
    float e = __expf(v - m);
    float s = e;
#pragma unroll
    for (int off = 32; off; off >>= 1) s += __shfl_xor(s, off, 64);
    out[(long long)node * 64 + lane] = e / s;
}

// ---------------------------------------------------------------------------
extern "C" void kernel_launch(void* const* d_in, const int* in_sizes, int n_in,
                              void* d_out, int out_size, void* d_ws, size_t ws_size,
                              hipStream_t stream)
{
    const float* y   = (const float*)d_in[0];   // [NN, F0]
    const int*   src = (const int*)  d_in[1];   // [NE]
    const int*   dst = (const int*)  d_in[2];   // [NE]
    const float* ew  = (const float*)d_in[3];   // [NE]
    const float* W1  = (const float*)d_in[4];   // [F0, F1]
    const float* b1  = (const float*)d_in[5];   // [F1]
    const float* W2  = (const float*)d_in[6];   // [F1, F2]
    const float* b2  = (const float*)d_in[7];   // [F2]

    float* out     = (float*)d_out;
    float* softout = out;                              // [NN, F2]
    float* h       = out + (size_t)NN * F2;            // [NN, F1] (embedding output)

    char*  ws   = (char*)d_ws;
    float* buf0 = (float*)ws;                              // support (51.2 MB max)
    float* buf1 = (float*)(ws + (size_t)NN * F1 * 4);      // agg     (51.2 MB max)

    // Layer 1: support1 = y @ W1   [NN, 128]
    gemm_kernel<64, 128, 32, 4, 8>
        <<<(NN + 63) / 64, 256, 0, stream>>>(y, W1, buf0, NN, F0, F1);

    hipMemsetAsync(buf1, 0, (size_t)NN * F1 * 4, stream);

    // agg1 = segment_sum(support1[src] * ew, dst)
    scatter_kernel<5>
        <<<(NE * 32) / 256, 256, 0, stream>>>((const float4*)buf0, src, dst, ew, buf1, NE);

    // h = leaky_relu(agg1 + b1)  -> written straight into d_out embedding slot
    bias_leaky_kernel
        <<<(NN * F1 / 4 + 255) / 256, 256, 0, stream>>>(
            (const float4*)buf1, (const float4*)b1, (float4*)h, NN * F1 / 4, F1 / 4 - 1);

    // Layer 2: support2 = h @ W2   [NN, 64]
    gemm_kernel<64, 64, 32, 4, 4>
        <<<(NN + 63) / 64, 256, 0, stream>>>(h, W2, buf0, NN, F1, F2);

    hipMemsetAsync(buf1, 0, (size_t)NN * F2 * 4, stream);

    // agg2 = segment_sum(support2[src] * ew, dst)
    scatter_kernel<4>
        <<<(NE * 16) / 256, 256, 0, stream>>>((const float4*)buf0, src, dst, ew, buf1, NE);

    // out = softmax(agg2 + b2, axis=1)
    softmax_kernel
        <<<NN / 4, 256, 0, stream>>>(buf1, b2, softout, NN);
}

// Round 2
// 831.973 us; speedup vs baseline: 5.4469x; 5.4469x over previous
//
#include <hip/hip_runtime.h>

#define NN 100000      // nodes
#define NE 1600000     // edges
#define F0 512         // NFEAT
#define F1 128         // NHID
#define F2 64          // NCLASS

// ---------------------------------------------------------------------------
// Tiled fp32 GEMM: C[M,N] = A[M,K] @ B[K,N], N == BN (single column block).
// ---------------------------------------------------------------------------
template<int BM, int BN, int BK, int TM, int TN>
__global__ __launch_bounds__(256)
void gemm_kernel(const float* __restrict__ A, const float* __restrict__ B,
                 float* __restrict__ C, int M, int K, int N)
{
    __shared__ float As[BK][BM + 4];   // A tile stored transposed (k-major)
    __shared__ float Bs[BK][BN];

    const int tx = threadIdx.x & 15;
    const int ty = threadIdx.x >> 4;
    const int row0 = blockIdx.x * BM;

    float acc[TM][TN];
#pragma unroll
    for (int i = 0; i < TM; i++)
#pragma unroll
        for (int j = 0; j < TN; j++) acc[i][j] = 0.f;

    for (int k0 = 0; k0 < K; k0 += BK) {
        constexpr int A4 = BM * BK / 4;
        for (int l = threadIdx.x; l < A4; l += 256) {
            int r  = l / (BK / 4);
            int kq = l % (BK / 4);
            int rg = row0 + r; if (rg >= M) rg = M - 1;
            float4 v = *(const float4*)(A + (long long)rg * K + k0 + kq * 4);
            As[kq * 4 + 0][r] = v.x;
            As[kq * 4 + 1][r] = v.y;
            As[kq * 4 + 2][r] = v.z;
            As[kq * 4 + 3][r] = v.w;
        }
        constexpr int B4 = BK * BN / 4;
        for (int l = threadIdx.x; l < B4; l += 256) {
            int kr = l / (BN / 4);
            int cq = l % (BN / 4);
            *(float4*)(&Bs[kr][cq * 4]) =
                *(const float4*)(B + (long long)(k0 + kr) * N + cq * 4);
        }
        __syncthreads();

#pragma unroll
        for (int k = 0; k < BK; k++) {
            float a[TM], b[TN];
#pragma unroll
            for (int i = 0; i < TM; i++) a[i] = As[k][ty * TM + i];
#pragma unroll
            for (int j = 0; j < TN; j++) b[j] = Bs[k][tx * TN + j];
#pragma unroll
            for (int i = 0; i < TM; i++)
#pragma unroll
                for (int j = 0; j < TN; j++)
                    acc[i][j] = fmaf(a[i], b[j], acc[i][j]);
        }
        __syncthreads();
    }

#pragma unroll
    for (int i = 0; i < TM; i++) {
        int rg = row0 + ty * TM + i;
        if (rg < M) {
#pragma unroll
            for (int j = 0; j < TN; j += 4) {
                float4 v = make_float4(acc[i][j], acc[i][j+1], acc[i][j+2], acc[i][j+3]);
                *(float4*)(C + (long long)rg * N + tx * TN + j) = v;
            }
        }
    }
}

// ---------------------------------------------------------------------------
// CSR build: histogram, 3-phase exclusive scan, fill (dst-sorted edge recs)
// ---------------------------------------------------------------------------
__global__ __launch_bounds__(256)
void hist_kernel(const int* __restrict__ dst, int* __restrict__ cnt, int ne)
{
    int e = blockIdx.x * 256 + threadIdx.x;
    if (e < ne) atomicAdd(&cnt[dst[e]], 1);
}

__global__ __launch_bounds__(256)
void scan1_kernel(const int* __restrict__ cnt, int* __restrict__ rowptr,
                  int* __restrict__ bsum, int n)
{
    __shared__ int s[256];
    int t = threadIdx.x;
    int i = blockIdx.x * 256 + t;
    int v = (i < n) ? cnt[i] : 0;
    s[t] = v;
    __syncthreads();
#pragma unroll
    for (int off = 1; off < 256; off <<= 1) {
        int x = (t >= off) ? s[t - off] : 0;
        __syncthreads();
        s[t] += x;
        __syncthreads();
    }
    if (i < n) rowptr[i] = s[t] - v;             // exclusive within block
    if (t == 255) bsum[blockIdx.x] = s[255];     // block total
}

__global__ __launch_bounds__(512)
void scan2_kernel(int* __restrict__ bsum, int nb, int* __restrict__ rowptr, int n, int ne)
{
    __shared__ int s[512];
    int t = threadIdx.x;
    int v = (t < nb) ? bsum[t] : 0;
    s[t] = v;
    __syncthreads();
#pragma unroll
    for (int off = 1; off < 512; off <<= 1) {
        int x = (t >= off) ? s[t - off] : 0;
        __syncthreads();
        s[t] += x;
        __syncthreads();
    }
    if (t < nb) bsum[t] = s[t] - v;              // exclusive block offsets
    if (t == 0) rowptr[n] = ne;                  // terminator
}

__global__ __launch_bounds__(256)
void scan3_kernel(int* __restrict__ rowptr, const int* __restrict__ bsum, int n)
{
    int i = blockIdx.x * 256 + threadIdx.x;
    if (i < n) rowptr[i] += bsum[i >> 8];
}

__global__ __launch_bounds__(256)
void fill_kernel(const int* __restrict__ src, const int* __restrict__ dst,
                 const float* __restrict__ ew, const int* __restrict__ rowptr,
                 int* __restrict__ fill, int2* __restrict__ rec, int ne)
{
    int e = blockIdx.x * 256 + threadIdx.x;
    if (e >= ne) return;
    int d = dst[e];
    int pos = rowptr[d] + atomicAdd(&fill[d], 1);
    rec[pos] = make_int2(src[e], __float_as_int(ew[e]));
}

// ---------------------------------------------------------------------------
// Fused aggregation layer 1: one wave per node, 2 feats/lane (F1=128).
// h[node] = leaky_relu(sum_e w_e * sup[src_e] + b1)
// ---------------------------------------------------------------------------
__global__ __launch_bounds__(256)
void agg1_kernel(const float2* __restrict__ sup, const int2* __restrict__ rec,
                 const int* __restrict__ rowptr, const float2* __restrict__ b1,
                 float2* __restrict__ h, int n)
{
    int node = blockIdx.x * 4 + (threadIdx.x >> 6);
    int lane = threadIdx.x & 63;
    if (node >= n) return;

    int j   = rowptr[node];
    int end = rowptr[node + 1];
    float2 acc = make_float2(0.f, 0.f);

    for (; j + 2 <= end; j += 2) {
        int2 r0 = rec[j];
        int2 r1 = rec[j + 1];
        float2 v0 = sup[(long long)r0.x * 64 + lane];
        float2 v1 = sup[(long long)r1.x * 64 + lane];
        float w0 = __int_as_float(r0.y);
        float w1 = __int_as_float(r1.y);
        acc.x = fmaf(v0.x, w0, acc.x);
        acc.y = fmaf(v0.y, w0, acc.y);
        acc.x = fmaf(v1.x, w1, acc.x);
        acc.y = fmaf(v1.y, w1, acc.y);
    }
    if (j < end) {
        int2 r0 = rec[j];
        float2 v0 = sup[(long long)r0.x * 64 + lane];
        float w0 = __int_as_float(r0.y);
        acc.x = fmaf(v0.x, w0, acc.x);
        acc.y = fmaf(v0.y, w0, acc.y);
    }

    float2 bb = b1[lane];
    acc.x += bb.x;
    acc.y += bb.y;
    acc.x = acc.x > 0.f ? acc.x : 0.01f * acc.x;
    acc.y = acc.y > 0.f ? acc.y : 0.01f * acc.y;
    h[(long long)node * 64 + lane] = acc;
}

// ---------------------------------------------------------------------------
// Fused aggregation layer 2 + softmax: one wave per node, 1 feat/lane (F2=64).
// ---------------------------------------------------------------------------
__global__ __launch_bounds__(256)
void agg2_kernel(const float* __restrict__ sup, const int2* __restrict__ rec,
                 const int* __restrict__ rowptr, const float* __restrict__ b2,
                 float* __restrict__ out, int n)
{
    int node = blockIdx.x * 4 + (threadIdx.x >> 6);
    int lane = threadIdx.x & 63;
    if (node >= n) return;

    int j   = rowptr[node];
    int end = rowptr[node + 1];
    float acc = 0.f;

    for (; j + 2 <= end; j += 2) {
        int2 r0 = rec[j];
        int2 r1 = rec[j + 1];
        float v0 = sup[(long long)r0.x * 64 + lane];
        float v1 = sup[(long long)r1.x * 64 + lane];
        acc = fmaf(v0, __int_as_float(r0.y), acc);
        acc = fmaf(v1, __int_as_float(r1.y), acc);
    }
    if (j < end) {
        int2 r0 = rec[j];
        float v0 = sup[(long long)r0.x * 64 + lane];
        acc = fmaf(v0, __int_as_float(r0.y), acc);
    }

    float v = acc + b2[lane];
    float m = v;
#pragma unroll
    for (int off = 32; off; off >>= 1) m = fmaxf(m, __shfl_xor(m, off, 64));
    float e = __expf(v - m);
    float s = e;
#pragma unroll
    for (int off = 32; off; off >>= 1) s += __shfl_xor(s, off, 64);
    out[(long long)node * 64 + lane] = e / s;
}

// ---------------------------------------------------------------------------
extern "C" void kernel_launch(void* const* d_in, const int* in_sizes, int n_in,
                              void* d_out, int out_size, void* d_ws, size_t ws_size,
                              hipStream_t stream)
{
    const float* y   = (const float*)d_in[0];   // [NN, F0]
    const int*   src = (const int*)  d_in[1];   // [NE]
    const int*   dst = (const int*)  d_in[2];   // [NE]
    const float* ew  = (const float*)d_in[3];   // [NE]
    const float* W1  = (const float*)d_in[4];   // [F0, F1]
    const float* b1  = (const float*)d_in[5];   // [F1]
    const float* W2  = (const float*)d_in[6];   // [F1, F2]
    const float* b2  = (const float*)d_in[7];   // [F2]

    float* out     = (float*)d_out;
    float* softout = out;                              // [NN, F2]
    float* h       = out + (size_t)NN * F2;            // [NN, F1] embedding

    // ---- workspace layout ----
    char* ws = (char*)d_ws;
    float* sup    = (float*)ws;                                 // 51.2 MB
    int2*  rec    = (int2*)(ws + (size_t)NN * F1 * 4);          // 12.8 MB
    int*   rowptr = (int*)((char*)rec + (size_t)NE * 8);        // NN+1
    int*   cnt    = rowptr + (NN + 2);                          // NN (histogram)
    int*   fill   = cnt + NN;                                   // NN (fill cursors)
    int*   bsum   = fill + NN;                                  // 512 block sums

    const int NB = (NN + 255) / 256;   // 391 scan blocks

    // ---- build dst-CSR (used by both layers) ----
    hipMemsetAsync(cnt, 0, (size_t)2 * NN * 4, stream);   // cnt + fill
    hist_kernel<<<(NE + 255) / 256, 256, 0, stream>>>(dst, cnt, NE);
    scan1_kernel<<<NB, 256, 0, stream>>>(cnt, rowptr, bsum, NN);
    scan2_kernel<<<1, 512, 0, stream>>>(bsum, NB, rowptr, NN, NE);
    scan3_kernel<<<NB, 256, 0, stream>>>(rowptr, bsum, NN);
    fill_kernel<<<(NE + 255) / 256, 256, 0, stream>>>(src, dst, ew, rowptr, fill, rec, NE);

    // ---- layer 1 ----
    gemm_kernel<64, 128, 32, 4, 8>
        <<<(NN + 63) / 64, 256, 0, stream>>>(y, W1, sup, NN, F0, F1);
    agg1_kernel<<<(NN + 3) / 4, 256, 0, stream>>>(
        (const float2*)sup, rec, rowptr, (const float2*)b1, (float2*)h, NN);

    // ---- layer 2 ----
    gemm_kernel<64, 64, 32, 4, 4>
        <<<(NN + 63) / 64, 256, 0, stream>>>(h, W2, sup, NN, F1, F2);
    agg2_kernel<<<(NN + 3) / 4, 256, 0, stream>>>(
        sup, rec, rowptr, b2, softout, NN);
}

// Round 3
// 729.446 us; speedup vs baseline: 6.2125x; 1.1406x over previous
//
#include <hip/hip_runtime.h>

#define NN 100000      // nodes
#define NE 1600000     // edges
#define F0 512         // NFEAT
#define F1 128         // NHID
#define F2 64          // NCLASS

typedef short bf16x8 __attribute__((ext_vector_type(8)));
typedef float f32x4  __attribute__((ext_vector_type(4)));

// fp32 -> bf16 (round-to-nearest-even, finite inputs)
static __device__ __forceinline__ unsigned short f2bf(float f) {
    unsigned int u = __float_as_uint(f);
    return (unsigned short)((u + 0x7FFFu + ((u >> 16) & 1u)) >> 16);
}

// ---------------------------------------------------------------------------
// Pre-transpose + convert weights: W1[512,128] -> W1t[128,512] bf16,
//                                  W2[128,64]  -> W2t[64,128]  bf16.
// ---------------------------------------------------------------------------
__global__ __launch_bounds__(256)
void wt_kernel(const float* __restrict__ W1, const float* __restrict__ W2,
               unsigned short* __restrict__ W1t, unsigned short* __restrict__ W2t)
{
    int i = blockIdx.x * 256 + threadIdx.x;
    if (i < F0 * F1) {
        int n = i / F0, k = i % F0;
        W1t[i] = f2bf(W1[k * F1 + n]);
    } else {
        int j = i - F0 * F1;
        if (j < F1 * F2) {
            int n = j / F1, k = j % F1;
            W2t[j] = f2bf(W2[k * F2 + n]);
        }
    }
}

// ---------------------------------------------------------------------------
// bf16 MFMA GEMM: C[M,N] = A[M,K] @ B[K,N], A fp32 (converted on the fly),
// B given pre-transposed bf16 as Bt[N,K]. N == BN (single col block).
// 256 threads = 4 waves; wave w computes rows [w*32, w*32+32) x all BN cols
// as 2 x TN tiles of 16x16, K-stepped by 32 (mfma_f32_16x16x32_bf16).
// ---------------------------------------------------------------------------
template<int BM, int BN, int BK, int TN>
__global__ __launch_bounds__(256)
void mfma_gemm(const float* __restrict__ A, const unsigned short* __restrict__ Bt,
               float* __restrict__ C, int M, int K, int N)
{
    constexpr int LDA = BK + 8;   // pad: 72 shorts = 144 B = 36 banks
    constexpr int LDB = BK + 8;
    __shared__ unsigned short As[BM * LDA];
    __shared__ unsigned short Bs[BN * LDB];

    const int tid  = threadIdx.x;
    const int wave = tid >> 6;
    const int lane = tid & 63;
    const int lr   = lane & 15;
    const int quad = lane >> 4;
    const int row0 = blockIdx.x * BM;

    f32x4 acc[2][TN];
#pragma unroll
    for (int i = 0; i < 2; i++)
#pragma unroll
        for (int j = 0; j < TN; j++) acc[i][j] = (f32x4)0.f;

    for (int k0 = 0; k0 < K; k0 += BK) {
        // --- stage A tile (BM x BK) fp32 -> bf16 ---
#pragma unroll
        for (int l = tid; l < BM * (BK / 4); l += 256) {
            int m  = l / (BK / 4);
            int kq = l % (BK / 4);
            int rg = row0 + m; if (rg >= M) rg = M - 1;
            float4 v = *(const float4*)(A + (long long)rg * K + k0 + kq * 4);
            ushort4 b = make_ushort4(f2bf(v.x), f2bf(v.y), f2bf(v.z), f2bf(v.w));
            *(ushort4*)(&As[m * LDA + kq * 4]) = b;
        }
        // --- stage B tile (BN x BK) from Bt[N,K] (already bf16) ---
#pragma unroll
        for (int l = tid; l < BN * (BK / 8); l += 256) {
            int n  = l / (BK / 8);
            int ko = l % (BK / 8);
            uint4 v = *(const uint4*)(Bt + (long long)n * K + k0 + ko * 8);
            *(uint4*)(&Bs[n * LDB + ko * 8]) = v;
        }
        __syncthreads();

#pragma unroll
        for (int kk = 0; kk < BK; kk += 32) {
            bf16x8 a[2], b[TN];
#pragma unroll
            for (int tm = 0; tm < 2; tm++)
                a[tm] = *(const bf16x8*)(&As[(wave * 32 + tm * 16 + lr) * LDA + kk + quad * 8]);
#pragma unroll
            for (int tn = 0; tn < TN; tn++)
                b[tn] = *(const bf16x8*)(&Bs[(tn * 16 + lr) * LDB + kk + quad * 8]);
#pragma unroll
            for (int tm = 0; tm < 2; tm++)
#pragma unroll
                for (int tn = 0; tn < TN; tn++)
                    acc[tm][tn] = __builtin_amdgcn_mfma_f32_16x16x32_bf16(
                        a[tm], b[tn], acc[tm][tn], 0, 0, 0);
        }
        __syncthreads();
    }

    // --- epilogue: C/D layout col=lane&15, row=quad*4+reg ---
#pragma unroll
    for (int tm = 0; tm < 2; tm++) {
#pragma unroll
        for (int r = 0; r < 4; r++) {
            int row = row0 + wave * 32 + tm * 16 + quad * 4 + r;
            if (row < M) {
#pragma unroll
                for (int tn = 0; tn < TN; tn++)
                    C[(long long)row * N + tn * 16 + lr] = acc[tm][tn][r];
            }
        }
    }
}

// ---------------------------------------------------------------------------
// CSR build: histogram, 3-phase exclusive scan, fill (dst-sorted edge recs)
// ---------------------------------------------------------------------------
__global__ __launch_bounds__(256)
void hist_kernel(const int* __restrict__ dst, int* __restrict__ cnt, int ne)
{
    int e = blockIdx.x * 256 + threadIdx.x;
    if (e < ne) atomicAdd(&cnt[dst[e]], 1);
}

__global__ __launch_bounds__(256)
void scan1_kernel(const int* __restrict__ cnt, int* __restrict__ rowptr,
                  int* __restrict__ bsum, int n)
{
    __shared__ int s[256];
    int t = threadIdx.x;
    int i = blockIdx.x * 256 + t;
    int v = (i < n) ? cnt[i] : 0;
    s[t] = v;
    __syncthreads();
#pragma unroll
    for (int off = 1; off < 256; off <<= 1) {
        int x = (t >= off) ? s[t - off] : 0;
        __syncthreads();
        s[t] += x;
        __syncthreads();
    }
    if (i < n) rowptr[i] = s[t] - v;
    if (t == 255) bsum[blockIdx.x] = s[255];
}

__global__ __launch_bounds__(512)
void scan2_kernel(int* __restrict__ bsum, int nb, int* __restrict__ rowptr, int n, int ne)
{
    __shared__ int s[512];
    int t = threadIdx.x;
    int v = (t < nb) ? bsum[t] : 0;
    s[t] = v;
    __syncthreads();
#pragma unroll
    for (int off = 1; off < 512; off <<= 1) {
        int x = (t >= off) ? s[t - off] : 0;
        __syncthreads();
        s[t] += x;
        __syncthreads();
    }
    if (t < nb) bsum[t] = s[t] - v;
    if (t == 0) rowptr[n] = ne;
}

__global__ __launch_bounds__(256)
void scan3_kernel(int* __restrict__ rowptr, const int* __restrict__ bsum, int n)
{
    int i = blockIdx.x * 256 + threadIdx.x;
    if (i < n) rowptr[i] += bsum[i >> 8];
}

__global__ __launch_bounds__(256)
void fill_kernel(const int* __restrict__ src, const int* __restrict__ dst,
                 const float* __restrict__ ew, const int* __restrict__ rowptr,
                 int* __restrict__ fill, int2* __restrict__ rec, int ne)
{
    int e = blockIdx.x * 256 + threadIdx.x;
    if (e >= ne) return;
    int d = dst[e];
    int pos = rowptr[d] + atomicAdd(&fill[d], 1);
    rec[pos] = make_int2(src[e], __float_as_int(ew[e]));
}

// ---------------------------------------------------------------------------
// Fused aggregation layer 1: one wave per node, 2 feats/lane (F1=128).
// ---------------------------------------------------------------------------
__global__ __launch_bounds__(256)
void agg1_kernel(const float2* __restrict__ sup, const int2* __restrict__ rec,
                 const int* __restrict__ rowptr, const float2* __restrict__ b1,
                 float2* __restrict__ h, int n)
{
    int node = blockIdx.x * 4 + (threadIdx.x >> 6);
    int lane = threadIdx.x & 63;
    if (node >= n) return;

    int j   = rowptr[node];
    int end = rowptr[node + 1];
    float2 acc = make_float2(0.f, 0.f);

    for (; j + 2 <= end; j += 2) {
        int2 r0 = rec[j];
        int2 r1 = rec[j + 1];
        float2 v0 = sup[(long long)r0.x * 64 + lane];
        float2 v1 = sup[(long long)r1.x * 64 + lane];
        float w0 = __int_as_float(r0.y);
        float w1 = __int_as_float(r1.y);
        acc.x = fmaf(v0.x, w0, acc.x);
        acc.y = fmaf(v0.y, w0, acc.y);
        acc.x = fmaf(v1.x, w1, acc.x);
        acc.y = fmaf(v1.y, w1, acc.y);
    }
    if (j < end) {
        int2 r0 = rec[j];
        float2 v0 = sup[(long long)r0.x * 64 + lane];
        float w0 = __int_as_float(r0.y);
        acc.x = fmaf(v0.x, w0, acc.x);
        acc.y = fmaf(v0.y, w0, acc.y);
    }

    float2 bb = b1[lane];
    acc.x += bb.x;
    acc.y += bb.y;
    acc.x = acc.x > 0.f ? acc.x : 0.01f * acc.x;
    acc.y = acc.y > 0.f ? acc.y : 0.01f * acc.y;
    h[(long long)node * 64 + lane] = acc;
}

// ---------------------------------------------------------------------------
// Fused aggregation layer 2 + softmax: one wave per node (F2=64).
// ---------------------------------------------------------------------------
__global__ __launch_bounds__(256)
void agg2_kernel(const float* __restrict__ sup, const int2* __restrict__ rec,
                 const int* __restrict__ rowptr, const float* __restrict__ b2,
                 float* __restrict__ out, int n)
{
    int node = blockIdx.x * 4 + (threadIdx.x >> 6);
    int lane = threadIdx.x & 63;
    if (node >= n) return;

    int j   = rowptr[node];
    int end = rowptr[node + 1];
    float acc = 0.f;

    for (; j + 2 <= end; j += 2) {
        int2 r0 = rec[j];
        int2 r1 = rec[j + 1];
        float v0 = sup[(long long)r0.x * 64 + lane];
        float v1 = sup[(long long)r1.x * 64 + lane];
        acc = fmaf(v0, __int_as_float(r0.y), acc);
        acc = fmaf(v1, __int_as_float(r1.y), acc);
    }
    if (j < end) {
        int2 r0 = rec[j];
        float v0 = sup[(long long)r0.x * 64 + lane];
        acc = fmaf(v0, __int_as_float(r0.y), acc);
    }

    float v = acc + b2[lane];
    float m = v;
#pragma unroll
    for (int off = 32; off; off >>= 1) m = fmaxf(m, __shfl_xor(m, off, 64));
    float e = __expf(v - m);
    float s = e;
#pragma unroll
    for (int off = 32; off; off >>= 1) s += __shfl_xor(s, off, 64);
    out[(long long)node * 64 + lane] = e / s;
}

// ---------------------------------------------------------------------------
extern "C" void kernel_launch(void* const* d_in, const int* in_sizes, int n_in,
                              void* d_out, int out_size, void* d_ws, size_t ws_size,
                              hipStream_t stream)
{
    const float* y   = (const float*)d_in[0];   // [NN, F0]
    const int*   src = (const int*)  d_in[1];   // [NE]
    const int*   dst = (const int*)  d_in[2];   // [NE]
    const float* ew  = (const float*)d_in[3];   // [NE]
    const float* W1  = (const float*)d_in[4];   // [F0, F1]
    const float* b1  = (const float*)d_in[5];   // [F1]
    const float* W2  = (const float*)d_in[6];   // [F1, F2]
    const float* b2  = (const float*)d_in[7];   // [F2]

    float* out     = (float*)d_out;
    float* softout = out;                              // [NN, F2]
    float* h       = out + (size_t)NN * F2;            // [NN, F1] embedding

    // ---- workspace layout ----
    char* ws = (char*)d_ws;
    float* sup    = (float*)ws;                                 // 51.2 MB
    int2*  rec    = (int2*)(ws + (size_t)NN * F1 * 4);          // 12.8 MB
    int*   rowptr = (int*)((char*)rec + (size_t)NE * 8);        // NN+1
    int*   cnt    = rowptr + (NN + 2);                          // NN
    int*   fill   = cnt + NN;                                   // NN
    int*   bsum   = fill + NN;                                  // 512
    unsigned short* W1t = (unsigned short*)(bsum + 512);        // 128 KB
    unsigned short* W2t = W1t + F0 * F1;                        // 16 KB

    const int NB = (NN + 255) / 256;

    // ---- weights: transpose + bf16 convert ----
    wt_kernel<<<(F0 * F1 + F1 * F2 + 255) / 256, 256, 0, stream>>>(W1, W2, W1t, W2t);

    // ---- build dst-CSR ----
    hipMemsetAsync(cnt, 0, (size_t)2 * NN * 4, stream);
    hist_kernel<<<(NE + 255) / 256, 256, 0, stream>>>(dst, cnt, NE);
    scan1_kernel<<<NB, 256, 0, stream>>>(cnt, rowptr, bsum, NN);
    scan2_kernel<<<1, 512, 0, stream>>>(bsum, NB, rowptr, NN, NE);
    scan3_kernel<<<NB, 256, 0, stream>>>(rowptr, bsum, NN);
    fill_kernel<<<(NE + 255) / 256, 256, 0, stream>>>(src, dst, ew, rowptr, fill, rec, NE);

    // ---- layer 1: support = y @ W1 (bf16 MFMA), then gather-agg ----
    mfma_gemm<128, 128, 64, 8>
        <<<(NN + 127) / 128, 256, 0, stream>>>(y, W1t, sup, NN, F0, F1);
    agg1_kernel<<<(NN + 3) / 4, 256, 0, stream>>>(
        (const float2*)sup, rec, rowptr, (const float2*)b1, (float2*)h, NN);

    // ---- layer 2: support = h @ W2 (bf16 MFMA), then gather-agg+softmax ----
    mfma_gemm<128, 64, 64, 4>
        <<<(NN + 127) / 128, 256, 0, stream>>>(h, W2t, sup, NN, F1, F2);
    agg2_kernel<<<(NN + 3) / 4, 256, 0, stream>>>(
        sup, rec, rowptr, b2, softout, NN);
}